// Round 5
// baseline (149.171 us; speedup 1.0000x reference)
//
#include <hip/hip_runtime.h>
#include <math.h>

#define NCH 384
#define RNK 5
#define NA  32
#define NSTART 384            // starts < NCH-NA+1 = 353; 384 bins for safety

// ---- happy-path ws word layout ----
#define WS_TOT   0                       // 1 f32 (total weight)
#define WS_MIN   1                       // 1 u32 (encoded min of lik_data)
#define WS_HIST  2                       // NSTART u32
#define WS_OFF   (WS_HIST + NSTART)      // NSTART+1 u32
#define WS_CUR   (WS_OFF + NSTART + 1)   // NSTART u32
#define WS_ZERO_WORDS (WS_CUR + NSTART)  // zero [0, WS_ZERO_WORDS)
// then: starts (n u16), order (n u32), ws2 (NSTART*BPB*TILE_W f32)

#define BPB    4              // blocks per bucket
#define SLICES 16             // wave-slices per bucket = BPB * 4 waves
#define TILE_W 192            // 160 numerator + 32 nan-weight partials

__device__ __forceinline__ bool finitef(float v) {
    return fabsf(v) <= 3.402823466e38f;   // NaN fails, +-inf exceeds
}
__device__ __forceinline__ unsigned fenc(float f) {
    unsigned u = __float_as_uint(f);
    return (u & 0x80000000u) ? ~u : (u | 0x80000000u);
}
__device__ __forceinline__ float fdec(unsigned u) {
    unsigned b = (u & 0x80000000u) ? (u ^ 0x80000000u) : ~u;
    return __uint_as_float(b);
}

// ---- pass 0: init (no hipMemsetAsync: rocclr fill costs ~40us in-graph) ----
__global__ void init_ws_kernel(unsigned* __restrict__ ws) {
    int i = blockIdx.x * blockDim.x + threadIdx.x;
    if (i < WS_ZERO_WORDS) ws[i] = (i == WS_MIN) ? 0xFFFFFFFFu : 0u;
}

// ---- pass 1: starts cache + histogram + total weight + global min(lik) ----
__global__ __launch_bounds__(256) void prep_kernel(
    const int* __restrict__ channels, const float* __restrict__ weights,
    const float* __restrict__ lik_data, int n, int nnz,
    unsigned* __restrict__ ws_u, float* __restrict__ ws_f,
    unsigned short* __restrict__ starts)
{
    const int i = blockIdx.x * 256 + threadIdx.x;
    float w = 0.f;
    if (i < n) {
        const int st = channels[(size_t)i * NA];   // channels[i][0] == start_i
        starts[i] = (unsigned short)st;
        atomicAdd(&ws_u[WS_HIST + st], 1u);
        w = weights[i];
    }
    #pragma unroll
    for (int o = 32; o; o >>= 1) w += __shfl_down(w, o);
    if ((threadIdx.x & 63) == 0) atomicAdd(&ws_f[WS_TOT], w);

    float m = 3.402823466e38f;
    const int stride = gridDim.x * blockDim.x;
    const int gtid = blockIdx.x * 256 + threadIdx.x;
    const int n4 = nnz >> 2;
    const float4* d4 = (const float4*)lik_data;
    for (int j = gtid; j < n4; j += stride) {
        float4 v = d4[j];
        m = fminf(m, fminf(fminf(v.x, v.y), fminf(v.z, v.w)));
    }
    for (int j = (n4 << 2) + gtid; j < nnz; j += stride) m = fminf(m, lik_data[j]);
    #pragma unroll
    for (int o = 32; o; o >>= 1) m = fminf(m, __shfl_down(m, o));
    if ((threadIdx.x & 63) == 0) atomicMin(&ws_u[WS_MIN], fenc(m));
}

// ---- pass 2: exclusive scan of the 384-bin histogram (single block) ----
__global__ __launch_bounds__(512) void scan_kernel(unsigned* __restrict__ ws_u)
{
    __shared__ unsigned s[NSTART];
    const int t = threadIdx.x;
    if (t < NSTART) s[t] = ws_u[WS_HIST + t];
    __syncthreads();
    for (int d = 1; d < NSTART; d <<= 1) {
        unsigned v = (t >= d && t < NSTART) ? s[t - d] : 0u;
        __syncthreads();
        if (t < NSTART) s[t] += v;
        __syncthreads();
    }
    if (t < NSTART) {
        unsigned excl = s[t] - ws_u[WS_HIST + t];
        ws_u[WS_OFF + t] = excl;
        ws_u[WS_CUR + t] = excl;
        if (t == NSTART - 1) ws_u[WS_OFF + NSTART] = s[t];
    }
}

// ---- pass 3: counting-sort scatter of spike ids ----
__global__ __launch_bounds__(256) void scatter_kernel(
    const unsigned short* __restrict__ starts, unsigned* __restrict__ cur,
    unsigned* __restrict__ order, int n)
{
    int i = blockIdx.x * 256 + threadIdx.x;
    if (i < n) {
        unsigned pos = atomicAdd(&cur[starts[i]], 1u);
        order[pos] = (unsigned)i;
    }
}

// ---- pass 4: bucketed accumulation -> private partial tiles (NO atomics
// to shared bins; the 1.18M same-address global atomic flush was the cost) ----
__global__ __launch_bounds__(256) void accum_kernel(
    const float* __restrict__ feats, const float* __restrict__ weights,
    const unsigned* __restrict__ order, const unsigned* __restrict__ off,
    float* __restrict__ ws2)
{
    __shared__ float s_tile[TILE_W];
    const int bid  = blockIdx.x;
    const int b    = bid % NSTART;
    const int j    = bid / NSTART;
    const int tid  = threadIdx.x;
    const int wave = tid >> 6;
    const int lane = tid & 63;
    const int slice = j * 4 + wave;
    const int lo = (int)off[b], hi = (int)off[b + 1];

    for (int i = tid; i < TILE_W; i += 256) s_tile[i] = 0.f;
    __syncthreads();

    float acc0 = 0.f, acc1 = 0.f, acc2 = 0.f, nanw = 0.f;
    const int k0 = lo + slice;
    int spike = 0; float w = 0.f;
    if (k0 < hi) { spike = (int)order[k0]; w = weights[spike]; }
    for (int k = k0; k < hi; k += SLICES) {
        const float* f = feats + (size_t)spike * (RNK * NA);
        int nspike = 0; float nw = 0.f;
        if (k + SLICES < hi) {            // prefetch next (spike, weight)
            nspike = (int)order[k + SLICES];
            nw = weights[nspike];
        }
        const float v0 = f[lane];          // elems [0,64)   ranks 0-1
        const float v1 = f[lane + 64];     // elems [64,128) ranks 2-3
        const float v2 = (lane < 32) ? f[lane + 128] : 0.f;  // rank 4
        const float r0 = __shfl(v0, lane & 31);  // rank-0 value of column a
        if (finitef(r0)) {
            acc0 += w * (finitef(v0) ? v0 : 0.f);
            acc1 += w * (finitef(v1) ? v1 : 0.f);
            if (lane < 32) acc2 += w * (finitef(v2) ? v2 : 0.f);
        } else if (lane < 32) {
            nanw += w;
        }
        spike = nspike; w = nw;
    }

    // combine 4 waves in LDS (tile elem for acc0 is exactly `lane`, etc.)
    atomicAdd(&s_tile[lane], acc0);
    atomicAdd(&s_tile[64 + lane], acc1);
    if (lane < 32) {
        atomicAdd(&s_tile[128 + lane], acc2);
        atomicAdd(&s_tile[160 + lane], nanw);
    }
    __syncthreads();

    float* dst = ws2 + (size_t)bid * TILE_W;   // private slot: plain stores
    for (int i = tid; i < TILE_W; i += 256) dst[i] = s_tile[i];
}

// ---- pass 5 (fused): emp_mean gather-reduce + finalize, and assignments ----
#define MAX_PER 16
__global__ __launch_bounds__(256) void final_kernel(
    const int* __restrict__ rows, const float* __restrict__ data,
    const float* __restrict__ tot_p, const unsigned* __restrict__ minw,
    const float* __restrict__ ws2, float* __restrict__ out,
    int n, int per, int assign_blocks)
{
    const int tid = threadIdx.x;
    if ((int)blockIdx.x >= assign_blocks) {
        // emp_mean: one thread per output element, gather partials from L2
        const int i = (blockIdx.x - assign_blocks) * 256 + tid;
        if (i < RNK * NCH) {
            const int c = i % NCH;
            const int r = i / NCH;
            const float tot = *tot_p;
            float s = 0.f, nb = 0.f;
            const int dbmax = (c + 1 < NA) ? (c + 1) : NA;  // b = c-db >= 0
            for (int db = 0; db < dbmax; ++db) {
                const int b = c - db;
                const float* t0 = ws2 + (size_t)b * TILE_W;
                #pragma unroll
                for (int jj = 0; jj < BPB; ++jj) {
                    const float* tj = t0 + (size_t)jj * NSTART * TILE_W;
                    s  += tj[r * 32 + db];
                    nb += tj[160 + db];
                }
            }
            out[i] = s / (tot - nb);
        }
        return;
    }

    // assignments: LDS-staged argmax with min-row tie-break
    __shared__ float sd[256 * MAX_PER];
    __shared__ int   sr[256 * MAX_PER];
    const int base = blockIdx.x * 256;
    const float offset = fdec(*minw) - 1.0f;

    if (per <= MAX_PER) {
        const int lim = min(256, n - base) * per;
        const size_t gbase = (size_t)base * per;
        for (int i = tid; i < lim; i += 256) {
            sd[i] = data[gbase + i];
            sr[i] = rows[gbase + i];
        }
        __syncthreads();
        const int spike = base + tid;
        if (spike >= n) return;
        float best_s = -3.402823466e38f;
        int best_row = 0x7FFFFFFF;
        const int o = tid * per;
        for (int j = 0; j < per; ++j) {
            float s = sd[o + j] - offset;    // same f32 op as reference
            int r = sr[o + j];
            if (s > best_s) { best_s = s; best_row = r; }
            else if (s == best_s && r < best_row) best_row = r;
        }
        out[RNK * NCH + spike] = (float)best_row;
    } else {
        const int spike = base + tid;
        if (spike >= n) return;
        const float* d  = data + (size_t)spike * per;
        const int*   rr = rows + (size_t)spike * per;
        float best_s = -3.402823466e38f;
        int best_row = 0x7FFFFFFF;
        for (int j = 0; j < per; ++j) {
            float s = d[j] - offset;
            int r = rr[j];
            if (s > best_s) { best_s = s; best_row = r; }
            else if (s == best_s && r < best_row) best_row = r;
        }
        out[RNK * NCH + spike] = (float)best_row;
    }
}

// ---- fallback path (ws too small): R2-style LDS-atomic accumulation ----
#define FB_NUM   0
#define FB_NANW  (RNK*NCH)
#define FB_TOT   (FB_NANW + NCH)
#define FB_MIN   (FB_TOT + 1)
#define FB_WORDS (FB_MIN + 1)

__global__ void fb_init_kernel(unsigned* __restrict__ ws) {
    int i = blockIdx.x * blockDim.x + threadIdx.x;
    if (i < FB_WORDS) ws[i] = (i == FB_MIN) ? 0xFFFFFFFFu : 0u;
}
__global__ __launch_bounds__(256) void fb_accum_kernel(
    const float* __restrict__ feats, const int* __restrict__ channels,
    const float* __restrict__ weights, float* __restrict__ ws, int n)
{
    __shared__ float s_num[RNK * NCH];
    __shared__ float s_nanw[NCH];
    __shared__ float s_total;
    const int tid = threadIdx.x;
    for (int i = tid; i < RNK * NCH; i += 256) s_num[i] = 0.f;
    for (int i = tid; i < NCH; i += 256) s_nanw[i] = 0.f;
    if (tid == 0) s_total = 0.f;
    __syncthreads();
    const int total = n * NA;
    const int stride = gridDim.x * blockDim.x;
    float tw = 0.f;
    for (int idx = blockIdx.x * blockDim.x + tid; idx < total; idx += stride) {
        const int spike = idx >> 5, a = idx & (NA - 1);
        const int ch = channels[idx];
        const float w = weights[spike];
        if (a == 0) tw += w;
        const float* f = feats + (size_t)spike * (RNK * NA) + a;
        const float v0 = f[0];
        if (finitef(v0)) {
            atomicAdd(&s_num[ch], w * v0);
            #pragma unroll
            for (int r = 1; r < RNK; ++r) {
                float v = f[r * NA];
                if (!finitef(v)) v = 0.f;
                atomicAdd(&s_num[r * NCH + ch], w * v);
            }
        } else atomicAdd(&s_nanw[ch], w);
    }
    #pragma unroll
    for (int off = 32; off; off >>= 1) tw += __shfl_down(tw, off);
    if ((tid & 63) == 0) atomicAdd(&s_total, tw);
    __syncthreads();
    for (int i = tid; i < RNK * NCH; i += 256)
        if (s_num[i] != 0.f) atomicAdd(&ws[FB_NUM + i], s_num[i]);
    for (int i = tid; i < NCH; i += 256)
        if (s_nanw[i] != 0.f) atomicAdd(&ws[FB_NANW + i], s_nanw[i]);
    if (tid == 0) atomicAdd(&ws[FB_TOT], s_total);
}
__global__ void fb_min_kernel(const float* __restrict__ data, int nnz,
                              unsigned* __restrict__ minw) {
    float m = 3.402823466e38f;
    for (int i = blockIdx.x * blockDim.x + threadIdx.x; i < nnz;
         i += gridDim.x * blockDim.x) m = fminf(m, data[i]);
    #pragma unroll
    for (int off = 32; off; off >>= 1) m = fminf(m, __shfl_down(m, off));
    if ((threadIdx.x & 63) == 0) atomicMin(minw, fenc(m));
}
__global__ void fb_finalize_kernel(const float* __restrict__ ws,
                                   float* __restrict__ out) {
    int i = blockIdx.x * blockDim.x + threadIdx.x;
    if (i < RNK * NCH) {
        int c = i % NCH;
        float cnt = ws[FB_TOT] - ws[FB_NANW + c];
        out[i] = ws[FB_NUM + i] / cnt;
    }
}
__global__ __launch_bounds__(256) void fb_assign_kernel(
    const int* __restrict__ rows, const float* __restrict__ data,
    const unsigned* __restrict__ minw, float* __restrict__ out, int n, int per)
{
    const int spike = blockIdx.x * 256 + threadIdx.x;
    if (spike >= n) return;
    const float offset = fdec(*minw) - 1.0f;
    const float* d  = data + (size_t)spike * per;
    const int*   rr = rows + (size_t)spike * per;
    float best_s = -3.402823466e38f;
    int best_row = 0x7FFFFFFF;
    for (int j = 0; j < per; ++j) {
        float s = d[j] - offset;
        int r = rr[j];
        if (s > best_s) { best_s = s; best_row = r; }
        else if (s == best_s && r < best_row) best_row = r;
    }
    out[RNK * NCH + spike] = (float)best_row;
}

extern "C" void kernel_launch(void* const* d_in, const int* in_sizes, int n_in,
                              void* d_out, int out_size, void* d_ws, size_t ws_size,
                              hipStream_t stream) {
    const float* feats    = (const float*)d_in[0];
    const int*   channels = (const int*)d_in[1];
    const float* weights  = (const float*)d_in[2];
    const int*   lik_rows = (const int*)d_in[3];
    const float* lik_data = (const float*)d_in[5];

    int n   = in_sizes[2];
    int nnz = in_sizes[3];
    int per = nnz / n;

    float*    out = (float*)d_out;
    unsigned* wsu = (unsigned*)d_ws;
    float*    wsf = (float*)d_ws;

    const size_t ws_starts = WS_ZERO_WORDS;                 // u16 array
    const size_t ws_order  = ws_starts + (size_t)(n + 1) / 2;
    const size_t ws_tile   = ws_order + (size_t)n;
    const size_t req_bytes = (ws_tile + (size_t)NSTART * BPB * TILE_W) * 4;

    if (ws_size >= req_bytes) {
        const int assign_blocks = (n + 255) / 256;
        const int emp_blocks    = (RNK * NCH + 255) / 256;
        init_ws_kernel<<<(WS_ZERO_WORDS + 255) / 256, 256, 0, stream>>>(wsu);
        prep_kernel<<<(n + 255) / 256, 256, 0, stream>>>(
            channels, weights, lik_data, n, nnz, wsu, wsf,
            (unsigned short*)(wsu + ws_starts));
        scan_kernel<<<1, 512, 0, stream>>>(wsu);
        scatter_kernel<<<(n + 255) / 256, 256, 0, stream>>>(
            (const unsigned short*)(wsu + ws_starts), wsu + WS_CUR,
            wsu + ws_order, n);
        accum_kernel<<<NSTART * BPB, 256, 0, stream>>>(
            feats, weights, wsu + ws_order, wsu + WS_OFF, wsf + ws_tile);
        final_kernel<<<assign_blocks + emp_blocks, 256, 0, stream>>>(
            lik_rows, lik_data, wsf + WS_TOT, wsu + WS_MIN, wsf + ws_tile,
            out, n, per, assign_blocks);
    } else {
        fb_init_kernel<<<(FB_WORDS + 255) / 256, 256, 0, stream>>>(wsu);
        fb_accum_kernel<<<1024, 256, 0, stream>>>(feats, channels, weights, wsf, n);
        fb_finalize_kernel<<<(RNK * NCH + 255) / 256, 256, 0, stream>>>(wsf, out);
        fb_min_kernel<<<256, 256, 0, stream>>>(lik_data, nnz, wsu + FB_MIN);
        fb_assign_kernel<<<(n + 255) / 256, 256, 0, stream>>>(
            lik_rows, lik_data, wsu + FB_MIN, out, n, per);
    }
}

// Round 6
// 72.349 us; speedup vs baseline: 2.0618x; 2.0618x over previous
//
#include <hip/hip_runtime.h>
#include <math.h>

#define NCH 384
#define RNK 5
#define NA  32
#define NSTART 384            // starts < NCH-NA+1 = 353; 384 bins for safety
#define CAP 1024              // per-bucket slot cap (avg ~186 for n=65536)
#define PREP_GRID 2048
#define BPB    8              // blocks per bucket
#define SLICES 32             // wave-slices per bucket = BPB * 4 waves
#define TILE_W 192            // 160 numerator + 32 nan-weight partials
#define MAX_PER 16
#define FLT_BIG 3.402823466e38f

// ---- ws word layout ----
#define WS_TOT   0                        // 1 f32 (total weight, final)
#define WS_MIN   1                        // 1 f32 (min of lik_data, final)
#define WS_CUR   2                        // NSTART u32 (bucket fill counters)
#define WS_TOTP  (WS_CUR + NSTART)        // PREP_GRID f32 partial totals
#define WS_MINP  (WS_TOTP + PREP_GRID)    // PREP_GRID f32 partial mins
#define WS_ORDER (WS_MINP + PREP_GRID)    // NSTART*CAP u32
#define WS_TILE  (WS_ORDER + NSTART*CAP)  // NSTART*BPB*TILE_W f32
#define WS_WORDS (WS_TILE + NSTART*BPB*TILE_W)

__device__ __forceinline__ bool finitef(float v) {
    return fabsf(v) <= FLT_BIG;   // NaN fails, +-inf exceeds
}

// ---- pass 0: zero bucket counters (no hipMemsetAsync in-graph: ~40us) ----
__global__ void init_ws_kernel(unsigned* __restrict__ ws) {
    int i = blockIdx.x * blockDim.x + threadIdx.x;
    if (i < NSTART) ws[WS_CUR + i] = 0u;
}

// ---- pass 1: direct bucket scatter + per-block weight-total & lik-min ----
__global__ __launch_bounds__(256) void prep_kernel(
    const int* __restrict__ channels, const float* __restrict__ weights,
    const float* __restrict__ lik_data, int n, int nnz,
    unsigned* __restrict__ ws_u, float* __restrict__ ws_f)
{
    const int tid  = threadIdx.x;
    const int lane = tid & 63;
    const int wave = tid >> 6;
    const int gtid = blockIdx.x * 256 + tid;
    const int gstride = gridDim.x * 256;

    float tw = 0.f;
    for (int i = gtid; i < n; i += gstride) {
        const int st = channels[(size_t)i * NA];   // channels[i][0] == start_i
        unsigned pos = atomicAdd(&ws_u[WS_CUR + st], 1u);
        if (pos < CAP) ws_u[WS_ORDER + (size_t)st * CAP + pos] = (unsigned)i;
        tw += weights[i];
    }

    float m = FLT_BIG;
    const int n4 = nnz >> 2;
    const float4* d4 = (const float4*)lik_data;
    for (int j = gtid; j < n4; j += gstride) {
        float4 v = d4[j];
        m = fminf(m, fminf(fminf(v.x, v.y), fminf(v.z, v.w)));
    }
    for (int j = (n4 << 2) + gtid; j < nnz; j += gstride)
        m = fminf(m, lik_data[j]);

    #pragma unroll
    for (int o = 32; o; o >>= 1) {
        tw += __shfl_down(tw, o);
        m = fminf(m, __shfl_down(m, o));
    }
    __shared__ float swt[4], swm[4];
    if (lane == 0) { swt[wave] = tw; swm[wave] = m; }
    __syncthreads();
    if (tid == 0) {
        ws_f[WS_TOTP + blockIdx.x] = swt[0] + swt[1] + swt[2] + swt[3];
        ws_f[WS_MINP + blockIdx.x] =
            fminf(fminf(swm[0], swm[1]), fminf(swm[2], swm[3]));
    }
}

// ---- pass 2: fold the 2048 per-block partials (single block) ----
__global__ __launch_bounds__(512) void reduce_kernel(float* __restrict__ ws_f)
{
    __shared__ float st[512], sm[512];
    const int tid = threadIdx.x;
    float t = 0.f, m = FLT_BIG;
    for (int i = tid; i < PREP_GRID; i += 512) {
        t += ws_f[WS_TOTP + i];
        m = fminf(m, ws_f[WS_MINP + i]);
    }
    st[tid] = t; sm[tid] = m;
    __syncthreads();
    for (int s = 256; s; s >>= 1) {
        if (tid < s) {
            st[tid] += st[tid + s];
            sm[tid] = fminf(sm[tid], sm[tid + s]);
        }
        __syncthreads();
    }
    if (tid == 0) { ws_f[WS_TOT] = st[0]; ws_f[WS_MIN] = sm[0]; }
}

// ---- pass 3: bucketed accumulation -> private partial tiles ----
// bucket b covers channels [b, b+NA). lane owns tile elems {lane, lane+64}
// (+ lane+128 for lane<32); elem e = r*32 + a.
__global__ __launch_bounds__(256) void accum_kernel(
    const float* __restrict__ feats, const float* __restrict__ weights,
    const unsigned* __restrict__ ws_u, float* __restrict__ ws2)
{
    __shared__ float s_tile[TILE_W];
    const int bid  = blockIdx.x;
    const int b    = bid >> 3;          // bid / BPB
    const int j    = bid & (BPB - 1);
    const int tid  = threadIdx.x;
    const int wave = tid >> 6;
    const int lane = tid & 63;
    const int slice = j * 4 + wave;
    int cnt = (int)ws_u[WS_CUR + b];
    if (cnt > CAP) cnt = CAP;
    const unsigned* order = ws_u + WS_ORDER + (size_t)b * CAP;

    for (int i = tid; i < TILE_W; i += 256) s_tile[i] = 0.f;
    __syncthreads();

    float acc0 = 0.f, acc1 = 0.f, acc2 = 0.f, nanw = 0.f;
    int spike = 0; float w = 0.f;
    if (slice < cnt) { spike = (int)order[slice]; w = weights[spike]; }
    for (int k = slice; k < cnt; k += SLICES) {
        const float* f = feats + (size_t)spike * (RNK * NA);
        int nspike = 0; float nw = 0.f;
        if (k + SLICES < cnt) {            // prefetch next (spike, weight)
            nspike = (int)order[k + SLICES];
            nw = weights[nspike];
        }
        const float v0 = f[lane];          // elems [0,64)   ranks 0-1
        const float v1 = f[lane + 64];     // elems [64,128) ranks 2-3
        const float v2 = (lane < 32) ? f[lane + 128] : 0.f;  // rank 4
        const float r0 = __shfl(v0, lane & 31);  // rank-0 value of column a
        if (finitef(r0)) {
            acc0 += w * (finitef(v0) ? v0 : 0.f);
            acc1 += w * (finitef(v1) ? v1 : 0.f);
            if (lane < 32) acc2 += w * (finitef(v2) ? v2 : 0.f);
        } else if (lane < 32) {
            nanw += w;
        }
        spike = nspike; w = nw;
    }

    atomicAdd(&s_tile[lane], acc0);
    atomicAdd(&s_tile[64 + lane], acc1);
    if (lane < 32) {
        atomicAdd(&s_tile[128 + lane], acc2);
        atomicAdd(&s_tile[160 + lane], nanw);
    }
    __syncthreads();

    float* dst = ws2 + (size_t)bid * TILE_W;   // private slot: plain stores
    for (int i = tid; i < TILE_W; i += 256) dst[i] = s_tile[i];
}

// ---- pass 4 (fused): assignments + emp_mean wave-gather ----
__global__ __launch_bounds__(256) void final_kernel(
    const int* __restrict__ rows, const float* __restrict__ data,
    const float* __restrict__ ws_f, const float* __restrict__ ws2,
    float* __restrict__ out, int n, int per, int assign_blocks)
{
    const int tid = threadIdx.x;
    if ((int)blockIdx.x >= assign_blocks) {
        // emp_mean: one WAVE per output element; lanes split (db, slice-half)
        const int widx = (blockIdx.x - assign_blocks) * 4 + (tid >> 6);
        const int lane = tid & 63;
        if (widx < RNK * NCH) {
            const int c = widx % NCH;
            const int r = widx / NCH;
            const int db = lane & 31;
            const int half = lane >> 5;
            float s = 0.f, nb = 0.f;
            const int b = c - db;
            if (b >= 0) {
                #pragma unroll
                for (int jj = 0; jj < BPB / 2; ++jj) {
                    const float* t =
                        ws2 + ((size_t)b * BPB + (jj * 2 + half)) * TILE_W;
                    s  += t[r * 32 + db];
                    nb += t[160 + db];
                }
            }
            #pragma unroll
            for (int o = 32; o; o >>= 1) {
                s  += __shfl_down(s, o);
                nb += __shfl_down(nb, o);
            }
            if (lane == 0) out[widx] = s / (ws_f[WS_TOT] - nb);
        }
        return;
    }

    // assignments: LDS-staged argmax with min-row tie-break
    __shared__ float sd[256 * MAX_PER];
    __shared__ int   sr[256 * MAX_PER];
    const int base = blockIdx.x * 256;
    const float offset = ws_f[WS_MIN] - 1.0f;

    if (per <= MAX_PER) {
        const int lim = min(256, n - base) * per;
        const size_t gbase = (size_t)base * per;
        for (int i = tid; i < lim; i += 256) {
            sd[i] = data[gbase + i];
            sr[i] = rows[gbase + i];
        }
        __syncthreads();
        const int spike = base + tid;
        if (spike >= n) return;
        float best_s = -FLT_BIG;
        int best_row = 0x7FFFFFFF;
        const int o = tid * per;
        for (int j = 0; j < per; ++j) {
            float s = sd[o + j] - offset;    // same f32 op as reference
            int r = sr[o + j];
            if (s > best_s) { best_s = s; best_row = r; }
            else if (s == best_s && r < best_row) best_row = r;
        }
        out[RNK * NCH + spike] = (float)best_row;
    } else {
        const int spike = base + tid;
        if (spike >= n) return;
        const float* d  = data + (size_t)spike * per;
        const int*   rr = rows + (size_t)spike * per;
        float best_s = -FLT_BIG;
        int best_row = 0x7FFFFFFF;
        for (int j = 0; j < per; ++j) {
            float s = d[j] - offset;
            int r = rr[j];
            if (s > best_s) { best_s = s; best_row = r; }
            else if (s == best_s && r < best_row) best_row = r;
        }
        out[RNK * NCH + spike] = (float)best_row;
    }
}

// ---- fallback path (ws too small): LDS-atomic accumulation ----
#define FB_NUM   0
#define FB_NANW  (RNK*NCH)
#define FB_TOT   (FB_NANW + NCH)
#define FB_MIN   (FB_TOT + 1)
#define FB_WORDS (FB_MIN + 1)

__device__ __forceinline__ unsigned fenc(float f) {
    unsigned u = __float_as_uint(f);
    return (u & 0x80000000u) ? ~u : (u | 0x80000000u);
}
__device__ __forceinline__ float fdec(unsigned u) {
    unsigned b = (u & 0x80000000u) ? (u ^ 0x80000000u) : ~u;
    return __uint_as_float(b);
}
__global__ void fb_init_kernel(unsigned* __restrict__ ws) {
    int i = blockIdx.x * blockDim.x + threadIdx.x;
    if (i < FB_WORDS) ws[i] = (i == FB_MIN) ? 0xFFFFFFFFu : 0u;
}
__global__ __launch_bounds__(256) void fb_accum_kernel(
    const float* __restrict__ feats, const int* __restrict__ channels,
    const float* __restrict__ weights, float* __restrict__ ws, int n)
{
    __shared__ float s_num[RNK * NCH];
    __shared__ float s_nanw[NCH];
    __shared__ float s_total;
    const int tid = threadIdx.x;
    for (int i = tid; i < RNK * NCH; i += 256) s_num[i] = 0.f;
    for (int i = tid; i < NCH; i += 256) s_nanw[i] = 0.f;
    if (tid == 0) s_total = 0.f;
    __syncthreads();
    const int total = n * NA;
    const int stride = gridDim.x * blockDim.x;
    float tw = 0.f;
    for (int idx = blockIdx.x * blockDim.x + tid; idx < total; idx += stride) {
        const int spike = idx >> 5, a = idx & (NA - 1);
        const int ch = channels[idx];
        const float w = weights[spike];
        if (a == 0) tw += w;
        const float* f = feats + (size_t)spike * (RNK * NA) + a;
        const float v0 = f[0];
        if (finitef(v0)) {
            atomicAdd(&s_num[ch], w * v0);
            #pragma unroll
            for (int r = 1; r < RNK; ++r) {
                float v = f[r * NA];
                if (!finitef(v)) v = 0.f;
                atomicAdd(&s_num[r * NCH + ch], w * v);
            }
        } else atomicAdd(&s_nanw[ch], w);
    }
    #pragma unroll
    for (int off = 32; off; off >>= 1) tw += __shfl_down(tw, off);
    if ((tid & 63) == 0) atomicAdd(&s_total, tw);
    __syncthreads();
    for (int i = tid; i < RNK * NCH; i += 256)
        if (s_num[i] != 0.f) atomicAdd(&ws[FB_NUM + i], s_num[i]);
    for (int i = tid; i < NCH; i += 256)
        if (s_nanw[i] != 0.f) atomicAdd(&ws[FB_NANW + i], s_nanw[i]);
    if (tid == 0) atomicAdd(&ws[FB_TOT], s_total);
}
__global__ void fb_min_kernel(const float* __restrict__ data, int nnz,
                              unsigned* __restrict__ minw) {
    float m = FLT_BIG;
    for (int i = blockIdx.x * blockDim.x + threadIdx.x; i < nnz;
         i += gridDim.x * blockDim.x) m = fminf(m, data[i]);
    #pragma unroll
    for (int off = 32; off; off >>= 1) m = fminf(m, __shfl_down(m, off));
    if ((threadIdx.x & 63) == 0) atomicMin(minw, fenc(m));
}
__global__ void fb_finalize_kernel(const float* __restrict__ ws,
                                   float* __restrict__ out) {
    int i = blockIdx.x * blockDim.x + threadIdx.x;
    if (i < RNK * NCH) {
        int c = i % NCH;
        float cnt = ws[FB_TOT] - ws[FB_NANW + c];
        out[i] = ws[FB_NUM + i] / cnt;
    }
}
__global__ __launch_bounds__(256) void fb_assign_kernel(
    const int* __restrict__ rows, const float* __restrict__ data,
    const unsigned* __restrict__ minw, float* __restrict__ out, int n, int per)
{
    const int spike = blockIdx.x * 256 + threadIdx.x;
    if (spike >= n) return;
    const float offset = fdec(*minw) - 1.0f;
    const float* d  = data + (size_t)spike * per;
    const int*   rr = rows + (size_t)spike * per;
    float best_s = -FLT_BIG;
    int best_row = 0x7FFFFFFF;
    for (int j = 0; j < per; ++j) {
        float s = d[j] - offset;
        int r = rr[j];
        if (s > best_s) { best_s = s; best_row = r; }
        else if (s == best_s && r < best_row) best_row = r;
    }
    out[RNK * NCH + spike] = (float)best_row;
}

extern "C" void kernel_launch(void* const* d_in, const int* in_sizes, int n_in,
                              void* d_out, int out_size, void* d_ws, size_t ws_size,
                              hipStream_t stream) {
    const float* feats    = (const float*)d_in[0];
    const int*   channels = (const int*)d_in[1];
    const float* weights  = (const float*)d_in[2];
    const int*   lik_rows = (const int*)d_in[3];
    const float* lik_data = (const float*)d_in[5];

    int n   = in_sizes[2];
    int nnz = in_sizes[3];
    int per = nnz / n;

    float*    out = (float*)d_out;
    unsigned* wsu = (unsigned*)d_ws;
    float*    wsf = (float*)d_ws;

    // happy path requires bucket capacity to hold the data (n/353 avg << CAP)
    const size_t req_bytes = (size_t)WS_WORDS * 4;
    const bool cap_ok = (n <= NSTART * CAP / 2);   // huge margin vs uniform starts

    if (ws_size >= req_bytes && cap_ok) {
        const int assign_blocks = (n + 255) / 256;
        const int emp_blocks    = (RNK * NCH + 4 * 4 - 1) / (4 * 4) ;  // 4 waves/blk... 
        // 1920 elements / 4 waves per block = 480 blocks
        const int emp_blk = (RNK * NCH + 3) / 4;
        (void)emp_blocks;
        init_ws_kernel<<<(NSTART + 255) / 256, 256, 0, stream>>>(wsu);
        prep_kernel<<<PREP_GRID, 256, 0, stream>>>(
            channels, weights, lik_data, n, nnz, wsu, wsf);
        reduce_kernel<<<1, 512, 0, stream>>>(wsf);
        accum_kernel<<<NSTART * BPB, 256, 0, stream>>>(
            feats, weights, wsu, wsf + WS_TILE);
        final_kernel<<<assign_blocks + emp_blk, 256, 0, stream>>>(
            lik_rows, lik_data, wsf, wsf + WS_TILE, out, n, per, assign_blocks);
    } else {
        fb_init_kernel<<<(FB_WORDS + 255) / 256, 256, 0, stream>>>(wsu);
        fb_accum_kernel<<<1024, 256, 0, stream>>>(feats, channels, weights, wsf, n);
        fb_finalize_kernel<<<(RNK * NCH + 255) / 256, 256, 0, stream>>>(wsf, out);
        fb_min_kernel<<<256, 256, 0, stream>>>(lik_data, nnz, wsu + FB_MIN);
        fb_assign_kernel<<<(n + 255) / 256, 256, 0, stream>>>(
            lik_rows, lik_data, wsu + FB_MIN, out, n, per);
    }
}